// Round 1
// 1217.062 us; speedup vs baseline: 1.0507x; 1.0507x over previous
//
#include <hip/hip_runtime.h>
#include <hip/hip_bf16.h>

// LSTM (all-tanh gates), B=128, T=1024, IN=512, UNITS=128.
// Plan:
//   k_wt   : W [512,512] f32 -> Wt bf16 [n][k] (transposed, k-contiguous) in ws
//   k_gemm : xW = x @ W, bf16 MFMA 16x16x32, A loaded f32->cvt, out f32 (or bf16 if ws small)
//   k_scan : 128 workgroups (one per batch elem), 512 threads, quad-per-column:
//            lane r of quad m computes all 4 gates over k in [32r,32r+32),
//            shfl_xor quad-reduce, redundant c/h update, ONE barrier per step.

#define UNITS 128
#define IN_DIM 512
#define BATCH 128
#define SEQ 1024
#define GATES 512            // 4*UNITS
#define M_ROWS (BATCH * SEQ) // 131072

typedef __attribute__((ext_vector_type(8))) short short8;
typedef __attribute__((ext_vector_type(4))) float floatx4;

__device__ __forceinline__ unsigned short f2bf(float f) {
    unsigned int x = __builtin_bit_cast(unsigned int, f);
    unsigned int r = (x + 0x7fffu + ((x >> 16) & 1u)) >> 16; // RNE
    return (unsigned short)r;
}
__device__ __forceinline__ float bf2f(unsigned short u) {
    unsigned int x = ((unsigned int)u) << 16;
    return __builtin_bit_cast(float, x);
}
__device__ __forceinline__ unsigned int pack2(float lo, float hi) {
    return (unsigned int)f2bf(lo) | ((unsigned int)f2bf(hi) << 16);
}

// tanh(x) = 1 - 2/(exp(2x)+1); clamp so exp stays finite. ~1e-7 abs error.
__device__ __forceinline__ float fast_tanh(float x) {
    float xc = fminf(12.0f, fmaxf(-12.0f, x));
    float e = __expf(2.0f * xc);
    return 1.0f - 2.0f * __builtin_amdgcn_rcpf(e + 1.0f);
}

// ---------------- W transpose + convert: Wt[n][k] = bf16(W[k][n]) ----------
__global__ void k_wt(const float* __restrict__ W, unsigned short* __restrict__ Wt) {
    int idx = blockIdx.x * 256 + threadIdx.x; // 0..262143, coalesced writes
    int n = idx >> 9;
    int k = idx & 511;
    Wt[idx] = f2bf(W[k * 512 + n]);
}

// ---------------- GEMM: C[m][n] = sum_k A[m][k] * W[k][n] ------------------
// 128x128 block tile, BK=32, 256 threads (4 waves, 2x2 of 64x64), bf16 MFMA.
// LDS padded to 40 elems/row (+16B) -> 2-way-max bank aliasing, 16B aligned rows.
template <bool XWF32>
__global__ void __launch_bounds__(256, 2)
k_gemm(const float* __restrict__ A, const unsigned short* __restrict__ Bt,
       void* __restrict__ Cout) {
    __shared__ __align__(16) unsigned short As[128 * 40];
    __shared__ __align__(16) unsigned short Bs[128 * 40];
    const int tid = threadIdx.x;
    const int m0 = blockIdx.y << 7;
    const int n0 = blockIdx.x << 7;
    const int l = tid & 63;
    const int w = tid >> 6;
    const int wr = (w >> 1) << 6; // wave row offset within tile
    const int wc = (w & 1) << 6;  // wave col offset
    const int lrow = l & 15;      // A/B fragment: own-index = lane%16
    const int lq = l >> 4;        // k-quarter: k = lq*8 + j

    floatx4 acc[4][4] = {};

    // staging map: thread -> (row srow, 16-elem half soff)
    const int srow = tid >> 1;
    const int soff = (tid & 1) << 4;
    const float* ap = A + (size_t)(m0 + srow) * 512 + soff;
    const unsigned short* bp = Bt + (size_t)(n0 + srow) * 512 + soff;
    unsigned short* as = &As[srow * 40 + soff];
    unsigned short* bs = &Bs[srow * 40 + soff];

    for (int k0 = 0; k0 < 512; k0 += 32) {
        float4 a0 = *(const float4*)(ap + k0);
        float4 a1 = *(const float4*)(ap + k0 + 4);
        float4 a2 = *(const float4*)(ap + k0 + 8);
        float4 a3 = *(const float4*)(ap + k0 + 12);
        uint4 b0 = *(const uint4*)(bp + k0);
        uint4 b1 = *(const uint4*)(bp + k0 + 8);
        __syncthreads(); // prev iteration's readers done before overwrite
        uint4 pa0, pa1;
        pa0.x = pack2(a0.x, a0.y); pa0.y = pack2(a0.z, a0.w);
        pa0.z = pack2(a1.x, a1.y); pa0.w = pack2(a1.z, a1.w);
        pa1.x = pack2(a2.x, a2.y); pa1.y = pack2(a2.z, a2.w);
        pa1.z = pack2(a3.x, a3.y); pa1.w = pack2(a3.z, a3.w);
        *(uint4*)as = pa0;
        *(uint4*)(as + 8) = pa1;
        *(uint4*)bs = b0;
        *(uint4*)(bs + 8) = b1;
        __syncthreads();
        short8 af[4], bfv[4];
#pragma unroll
        for (int mi = 0; mi < 4; ++mi)
            af[mi] = *(const short8*)&As[(wr + mi * 16 + lrow) * 40 + lq * 8];
#pragma unroll
        for (int ni = 0; ni < 4; ++ni)
            bfv[ni] = *(const short8*)&Bs[(wc + ni * 16 + lrow) * 40 + lq * 8];
#pragma unroll
        for (int mi = 0; mi < 4; ++mi)
#pragma unroll
            for (int ni = 0; ni < 4; ++ni)
                acc[mi][ni] = __builtin_amdgcn_mfma_f32_16x16x32_bf16(
                    af[mi], bfv[ni], acc[mi][ni], 0, 0, 0);
    }
    // epilogue: C/D layout col=lane&15, row=(lane>>4)*4+r
#pragma unroll
    for (int mi = 0; mi < 4; ++mi) {
#pragma unroll
        for (int ni = 0; ni < 4; ++ni) {
            int row = m0 + wr + mi * 16 + lq * 4;
            int col = n0 + wc + ni * 16 + lrow;
            if (XWF32) {
                float* Cf = (float*)Cout;
#pragma unroll
                for (int r = 0; r < 4; ++r)
                    Cf[(size_t)(row + r) * 512 + col] = acc[mi][ni][r];
            } else {
                unsigned short* Cb = (unsigned short*)Cout;
#pragma unroll
                for (int r = 0; r < 4; ++r)
                    Cb[(size_t)(row + r) * 512 + col] = f2bf(acc[mi][ni][r]);
            }
        }
    }
}

// ---------------- recurrent scan: one workgroup per batch element ----------
// 512 threads = 128 quads. Quad m (thread j: m=j>>2, r=j&3) owns h-column m.
// Lane r holds U[k][g*128+m] for k in [32r,32r+32), all 4 gates (128 VGPRs).
// Per step: partial dots for 4 gates -> shfl_xor(1),(2) quad reduce -> every
// lane computes gates + c/h redundantly (c in registers). h goes through a
// double-buffered LDS array (quarter-padded: 4x40 floats per buffer so the 4
// per-quad read streams hit disjoint banks). ONE barrier per timestep.
template <bool XWF32>
__global__ void __launch_bounds__(512, 2)
k_scan(const void* __restrict__ xwv, const float* __restrict__ U,
       const float* __restrict__ bias, float* __restrict__ out) {
    __shared__ __align__(16) float hbuf[2 * 160]; // [buf][quarter*40 + (m&31)]
    const int j = threadIdx.x;
    const int bb = blockIdx.x;
    const int m = j >> 2; // h column 0..127
    const int r = j & 3;  // k-quarter

    // U slices: u{g}[kk] = U[(32r+kk)*512 + g*128 + m]
    float u0[32], u1[32], u2[32], u3[32];
#pragma unroll
    for (int kk = 0; kk < 32; ++kk) {
        const float* Up = U + (size_t)(r * 32 + kk) * 512 + m;
        u0[kk] = Up[0];
        u1[kk] = Up[128];
        u2[kk] = Up[256];
        u3[kk] = Up[384];
    }
    const float bj = bias[r * 128 + m]; // bias for this lane's own gate r

    if (j < 160) hbuf[j] = 0.0f; // h0 = 0 (buffer 0, incl. pad)
    __syncthreads();

    // per-lane xw stream: own gate r only, column r*128+m
    const float* xwf = (const float*)xwv + (size_t)bb * SEQ * 512 + r * 128 + m;
    const unsigned short* xwb =
        (const unsigned short*)xwv + (size_t)bb * SEQ * 512 + r * 128 + m;

    float c = 0.0f, hval = 0.0f;
    float xw_cur = XWF32 ? xwf[0] : bf2f(xwb[0]);
    for (int t = 0; t < SEQ; ++t) {
        float xw_next = 0.0f;
        if (t + 1 < SEQ)
            xw_next = XWF32 ? xwf[(size_t)(t + 1) * 512]
                            : bf2f(xwb[(size_t)(t + 1) * 512]);

        // own-gate xw+bias folded into own accumulator pre-reduce
        const float xb = xw_cur + bj;
        float a0 = (r == 0) ? xb : 0.0f;
        float a1 = (r == 1) ? xb : 0.0f;
        float a2 = (r == 2) ? xb : 0.0f;
        float a3 = (r == 3) ? xb : 0.0f;

        const float4* h4 =
            (const float4*)(hbuf + (t & 1) * 160 + r * 40); // this lane's k-quarter
#pragma unroll
        for (int i = 0; i < 8; ++i) {
            float4 hv = h4[i];
            a0 = fmaf(hv.x, u0[4 * i + 0], a0);
            a1 = fmaf(hv.x, u1[4 * i + 0], a1);
            a2 = fmaf(hv.x, u2[4 * i + 0], a2);
            a3 = fmaf(hv.x, u3[4 * i + 0], a3);
            a0 = fmaf(hv.y, u0[4 * i + 1], a0);
            a1 = fmaf(hv.y, u1[4 * i + 1], a1);
            a2 = fmaf(hv.y, u2[4 * i + 1], a2);
            a3 = fmaf(hv.y, u3[4 * i + 1], a3);
            a0 = fmaf(hv.z, u0[4 * i + 2], a0);
            a1 = fmaf(hv.z, u1[4 * i + 2], a1);
            a2 = fmaf(hv.z, u2[4 * i + 2], a2);
            a3 = fmaf(hv.z, u3[4 * i + 2], a3);
            a0 = fmaf(hv.w, u0[4 * i + 3], a0);
            a1 = fmaf(hv.w, u1[4 * i + 3], a1);
            a2 = fmaf(hv.w, u2[4 * i + 3], a2);
            a3 = fmaf(hv.w, u3[4 * i + 3], a3);
        }
        // quad reduce (intra-wave, no barrier): lanes r^1, r^2
        a0 += __shfl_xor(a0, 1);
        a1 += __shfl_xor(a1, 1);
        a2 += __shfl_xor(a2, 1);
        a3 += __shfl_xor(a3, 1);
        a0 += __shfl_xor(a0, 2);
        a1 += __shfl_xor(a1, 2);
        a2 += __shfl_xor(a2, 2);
        a3 += __shfl_xor(a3, 2);

        // all 4 lanes redundantly: gates i,f,g,o (all tanh), c/h update
        const float gi = fast_tanh(a0);
        const float gf = fast_tanh(a1);
        const float gg = fast_tanh(a2);
        const float go = fast_tanh(a3);
        c = fmaf(gf, c, gi * gg);
        hval = go * fast_tanh(c);

        if (r == 0)
            hbuf[((t + 1) & 1) * 160 + (m >> 5) * 40 + (m & 31)] = hval;
        __syncthreads(); // write of buf[t+1] visible before next step's reads
        xw_cur = xw_next;
    }
    if (r == 0) out[bb * UNITS + m] = hval;
}

// ---------------------------------------------------------------------------
extern "C" void kernel_launch(void* const* d_in, const int* in_sizes, int n_in,
                              void* d_out, int out_size, void* d_ws, size_t ws_size,
                              hipStream_t stream) {
    const float* x = (const float*)d_in[0]; // [128,1024,512]
    const float* W = (const float*)d_in[1]; // [512,512]
    const float* U = (const float*)d_in[2]; // [128,512]
    const float* b = (const float*)d_in[3]; // [512]
    float* out = (float*)d_out;             // [128,128]

    char* ws = (char*)d_ws;
    const size_t WT_BYTES = (size_t)512 * 512 * 2; // 512 KB
    unsigned short* Wt = (unsigned short*)ws;
    void* xw = (void*)(ws + WT_BYTES);
    const size_t XW_F32_BYTES = (size_t)M_ROWS * 512 * 4; // 256 MB
    const bool f32path = (ws_size >= WT_BYTES + XW_F32_BYTES);

    k_wt<<<dim3(1024), dim3(256), 0, stream>>>(W, Wt);

    dim3 ggrid(4, 1024); // N-tiles x M-tiles
    if (f32path) {
        k_gemm<true><<<ggrid, dim3(256), 0, stream>>>(x, Wt, xw);
        k_scan<true><<<dim3(128), dim3(512), 0, stream>>>(xw, U, b, out);
    } else {
        k_gemm<false><<<ggrid, dim3(256), 0, stream>>>(x, Wt, xw);
        k_scan<false><<<dim3(128), dim3(512), 0, stream>>>(xw, U, b, out);
    }
}

// Round 2
// 1043.341 us; speedup vs baseline: 1.2256x; 1.1665x over previous
//
#include <hip/hip_runtime.h>
#include <hip/hip_bf16.h>

// LSTM (all-tanh gates), B=128, T=1024, IN=512, UNITS=128.
// Plan:
//   k_wt   : W [512,512] f32 -> Wt bf16 [n][k] (transposed, k-contiguous) in ws
//   k_gemm : xW = x @ W, bf16 MFMA 16x16x32, A loaded f32->cvt, out f32 (or bf16 if ws small)
//   k_scan : 128 workgroups (one per batch elem), 512 threads, quad-per-column:
//            lane r of quad m computes partial dots (all 4 gates) over k in
//            [32r,32r+32) with v_pk_fma_f32; DPP transposed quad-reduce leaves
//            gate r on lane r (1 tanh/lane); DPP quad-broadcast of gates;
//            redundant c/h update; ONE barrier per step.

#define UNITS 128
#define IN_DIM 512
#define BATCH 128
#define SEQ 1024
#define GATES 512            // 4*UNITS
#define M_ROWS (BATCH * SEQ) // 131072

typedef __attribute__((ext_vector_type(8))) short short8;
typedef __attribute__((ext_vector_type(4))) float floatx4;
typedef __attribute__((ext_vector_type(4))) float fv4;
typedef __attribute__((ext_vector_type(2))) float fv2;

__device__ __forceinline__ unsigned short f2bf(float f) {
    unsigned int x = __builtin_bit_cast(unsigned int, f);
    unsigned int r = (x + 0x7fffu + ((x >> 16) & 1u)) >> 16; // RNE
    return (unsigned short)r;
}
__device__ __forceinline__ float bf2f(unsigned short u) {
    unsigned int x = ((unsigned int)u) << 16;
    return __builtin_bit_cast(float, x);
}
__device__ __forceinline__ unsigned int pack2(float lo, float hi) {
    return (unsigned int)f2bf(lo) | ((unsigned int)f2bf(hi) << 16);
}

// tanh(x) = 1 - 2/(exp2(2*log2e*x)+1); clamp keeps exp2 finite. ~1e-7 abs err.
__device__ __forceinline__ float fast_tanh(float x) {
    float y = fminf(34.6f, fmaxf(-34.6f, x * 2.88539008f));
    float e = __builtin_amdgcn_exp2f(y);
    return 1.0f - 2.0f * __builtin_amdgcn_rcpf(e + 1.0f);
}

// DPP helpers (quad_perm only -> works at any lane position, full exec).
template <int CTRL>
__device__ __forceinline__ float dppf(float x) {
    int xi = __builtin_bit_cast(int, x);
    int r = __builtin_amdgcn_update_dpp(0, xi, CTRL, 0xF, 0xF, true);
    return __builtin_bit_cast(float, r);
}
#define DPP_XOR1 0xB1 // [1,0,3,2]
#define DPP_XOR2 0x4E // [2,3,0,1]
#define DPP_BC0 0x00
#define DPP_BC1 0x55
#define DPP_BC2 0xAA
#define DPP_BC3 0xFF

__device__ __forceinline__ void pk_fma(fv2& acc, fv2 a, fv2 b) {
    asm("v_pk_fma_f32 %0, %1, %2, %0" : "+v"(acc) : "v"(a), "v"(b));
}

// ---------------- W transpose + convert: Wt[n][k] = bf16(W[k][n]) ----------
__global__ void k_wt(const float* __restrict__ W, unsigned short* __restrict__ Wt) {
    int idx = blockIdx.x * 256 + threadIdx.x; // 0..262143, coalesced writes
    int n = idx >> 9;
    int k = idx & 511;
    Wt[idx] = f2bf(W[k * 512 + n]);
}

// ---------------- GEMM: C[m][n] = sum_k A[m][k] * W[k][n] ------------------
// 128x128 block tile, BK=32, 256 threads (4 waves, 2x2 of 64x64), bf16 MFMA.
// LDS padded to 40 elems/row (+16B) -> 2-way-max bank aliasing, 16B aligned rows.
template <bool XWF32>
__global__ void __launch_bounds__(256, 2)
k_gemm(const float* __restrict__ A, const unsigned short* __restrict__ Bt,
       void* __restrict__ Cout) {
    __shared__ __align__(16) unsigned short As[128 * 40];
    __shared__ __align__(16) unsigned short Bs[128 * 40];
    const int tid = threadIdx.x;
    const int m0 = blockIdx.y << 7;
    const int n0 = blockIdx.x << 7;
    const int l = tid & 63;
    const int w = tid >> 6;
    const int wr = (w >> 1) << 6; // wave row offset within tile
    const int wc = (w & 1) << 6;  // wave col offset
    const int lrow = l & 15;      // A/B fragment: own-index = lane%16
    const int lq = l >> 4;        // k-quarter: k = lq*8 + j

    floatx4 acc[4][4] = {};

    // staging map: thread -> (row srow, 16-elem half soff)
    const int srow = tid >> 1;
    const int soff = (tid & 1) << 4;
    const float* ap = A + (size_t)(m0 + srow) * 512 + soff;
    const unsigned short* bp = Bt + (size_t)(n0 + srow) * 512 + soff;
    unsigned short* as = &As[srow * 40 + soff];
    unsigned short* bs = &Bs[srow * 40 + soff];

    for (int k0 = 0; k0 < 512; k0 += 32) {
        float4 a0 = *(const float4*)(ap + k0);
        float4 a1 = *(const float4*)(ap + k0 + 4);
        float4 a2 = *(const float4*)(ap + k0 + 8);
        float4 a3 = *(const float4*)(ap + k0 + 12);
        uint4 b0 = *(const uint4*)(bp + k0);
        uint4 b1 = *(const uint4*)(bp + k0 + 8);
        __syncthreads(); // prev iteration's readers done before overwrite
        uint4 pa0, pa1;
        pa0.x = pack2(a0.x, a0.y); pa0.y = pack2(a0.z, a0.w);
        pa0.z = pack2(a1.x, a1.y); pa0.w = pack2(a1.z, a1.w);
        pa1.x = pack2(a2.x, a2.y); pa1.y = pack2(a2.z, a2.w);
        pa1.z = pack2(a3.x, a3.y); pa1.w = pack2(a3.z, a3.w);
        *(uint4*)as = pa0;
        *(uint4*)(as + 8) = pa1;
        *(uint4*)bs = b0;
        *(uint4*)(bs + 8) = b1;
        __syncthreads();
        short8 af[4], bfv[4];
#pragma unroll
        for (int mi = 0; mi < 4; ++mi)
            af[mi] = *(const short8*)&As[(wr + mi * 16 + lrow) * 40 + lq * 8];
#pragma unroll
        for (int ni = 0; ni < 4; ++ni)
            bfv[ni] = *(const short8*)&Bs[(wc + ni * 16 + lrow) * 40 + lq * 8];
#pragma unroll
        for (int mi = 0; mi < 4; ++mi)
#pragma unroll
            for (int ni = 0; ni < 4; ++ni)
                acc[mi][ni] = __builtin_amdgcn_mfma_f32_16x16x32_bf16(
                    af[mi], bfv[ni], acc[mi][ni], 0, 0, 0);
    }
    // epilogue: C/D layout col=lane&15, row=(lane>>4)*4+r
#pragma unroll
    for (int mi = 0; mi < 4; ++mi) {
#pragma unroll
        for (int ni = 0; ni < 4; ++ni) {
            int row = m0 + wr + mi * 16 + lq * 4;
            int col = n0 + wc + ni * 16 + lrow;
            if (XWF32) {
                float* Cf = (float*)Cout;
#pragma unroll
                for (int r = 0; r < 4; ++r)
                    Cf[(size_t)(row + r) * 512 + col] = acc[mi][ni][r];
            } else {
                unsigned short* Cb = (unsigned short*)Cout;
#pragma unroll
                for (int r = 0; r < 4; ++r)
                    Cb[(size_t)(row + r) * 512 + col] = f2bf(acc[mi][ni][r]);
            }
        }
    }
}

// ---------------- recurrent scan: one workgroup per batch element ----------
// 512 threads = 128 quads. Quad m (thread j: m=j>>2, r=j&3) owns h-column m.
// Lane r holds U[k][g*128+m] for k in [32r,32r+32), all 4 gates, as 64 float2
// (128 VGPRs; launch_bounds(512,1) so they are NOT pushed to AGPRs — only one
// block ever resides per CU with 128 blocks on 256 CUs, so no occupancy loss).
// Per step:
//   64 v_pk_fma_f32 partial dots -> DPP transposed quad-reduce (lane r gets
//   gate r fully reduced) -> z = sigma + xw(own col) + b -> ONE tanh ->
//   4 DPP quad-broadcasts -> redundant c/h update (c in regs) ->
//   r==0 writes h to double-buffered LDS -> ONE barrier.
template <bool XWF32>
__global__ void __launch_bounds__(512, 1)
k_scan(const void* __restrict__ xwv, const float* __restrict__ U,
       const float* __restrict__ bias, float* __restrict__ out) {
    __shared__ __align__(16) float hbuf[2 * 160]; // [buf][quarter*40 + (m&31)]
    const int j = threadIdx.x;
    const int bb = blockIdx.x;
    const int m = j >> 2; // h column 0..127
    const int r = j & 3;  // k-quarter AND own-gate index

    // U slices, packed along k: u2[g][i] = (U[k0+2i][g*128+m], U[k0+2i+1][g*128+m])
    fv2 u2[4][16];
#pragma unroll
    for (int i = 0; i < 16; ++i) {
        const float* Up0 = U + (size_t)(r * 32 + 2 * i) * 512 + m;
        const float* Up1 = Up0 + 512;
        u2[0][i] = (fv2){Up0[0], Up1[0]};
        u2[1][i] = (fv2){Up0[128], Up1[128]};
        u2[2][i] = (fv2){Up0[256], Up1[256]};
        u2[3][i] = (fv2){Up0[384], Up1[384]};
    }
    const float bj = bias[r * 128 + m]; // bias for this lane's own gate r
    const int p = r & 1;
    const int q = (r >> 1) & 1;

    if (j < 160) hbuf[j] = 0.0f; // h0 = 0 (buffer 0, incl. pad)
    __syncthreads();

    // per-lane xw stream: own gate r only, column r*128+m
    const float* xwf = (const float*)xwv + (size_t)bb * SEQ * 512 + r * 128 + m;
    const unsigned short* xwb =
        (const unsigned short*)xwv + (size_t)bb * SEQ * 512 + r * 128 + m;

    float c = 0.0f, hval = 0.0f;
    float xb_cur = (XWF32 ? xwf[0] : bf2f(xwb[0])) + bj;
    for (int t = 0; t < SEQ; ++t) {
        float xw_next = 0.0f;
        if (t + 1 < SEQ)
            xw_next = XWF32 ? xwf[(size_t)(t + 1) * 512]
                            : bf2f(xwb[(size_t)(t + 1) * 512]);

        fv2 A0 = {0.f, 0.f}, A1 = {0.f, 0.f}, A2 = {0.f, 0.f}, A3 = {0.f, 0.f};
        const fv4* h4 =
            (const fv4*)(hbuf + (t & 1) * 160 + r * 40); // this lane's k-quarter
#pragma unroll
        for (int i = 0; i < 8; ++i) {
            fv4 hv = h4[i];
            fv2 hl = hv.lo;
            fv2 hh = hv.hi;
            pk_fma(A0, hl, u2[0][2 * i]);
            pk_fma(A1, hl, u2[1][2 * i]);
            pk_fma(A2, hl, u2[2][2 * i]);
            pk_fma(A3, hl, u2[3][2 * i]);
            pk_fma(A0, hh, u2[0][2 * i + 1]);
            pk_fma(A1, hh, u2[1][2 * i + 1]);
            pk_fma(A2, hh, u2[2][2 * i + 1]);
            pk_fma(A3, hh, u2[3][2 * i + 1]);
        }
        float s0 = A0.x + A0.y;
        float s1 = A1.x + A1.y;
        float s2 = A2.x + A2.y;
        float s3 = A3.x + A3.y;

        // transposed quad-reduce: lane r ends with sigma = full dot of gate r
        float va = p ? s1 : s0;
        float oa = p ? s0 : s1;
        float vb = p ? s3 : s2;
        float ob = p ? s2 : s3;
        float a01 = va + dppf<DPP_XOR1>(oa);
        float a23 = vb + dppf<DPP_XOR1>(ob);
        float vv = q ? a23 : a01;
        float oo = q ? a01 : a23;
        float sigma = vv + dppf<DPP_XOR2>(oo);

        float tg = fast_tanh(sigma + xb_cur); // own gate, all-tanh variant

        // quad broadcast of the four gate activations (Keras order i,f,g,o)
        float gi = dppf<DPP_BC0>(tg);
        float gf = dppf<DPP_BC1>(tg);
        float gg = dppf<DPP_BC2>(tg);
        float go = dppf<DPP_BC3>(tg);
        c = fmaf(gf, c, gi * gg);
        hval = go * fast_tanh(c);

        if (r == 0)
            hbuf[((t + 1) & 1) * 160 + (m >> 5) * 40 + (m & 31)] = hval;
        __syncthreads(); // write of buf[t+1] visible before next step's reads
        xb_cur = xw_next + bj;
    }
    if (r == 0) out[bb * UNITS + m] = hval;
}

// ---------------------------------------------------------------------------
extern "C" void kernel_launch(void* const* d_in, const int* in_sizes, int n_in,
                              void* d_out, int out_size, void* d_ws, size_t ws_size,
                              hipStream_t stream) {
    const float* x = (const float*)d_in[0]; // [128,1024,512]
    const float* W = (const float*)d_in[1]; // [512,512]
    const float* U = (const float*)d_in[2]; // [128,512]
    const float* b = (const float*)d_in[3]; // [512]
    float* out = (float*)d_out;             // [128,128]

    char* ws = (char*)d_ws;
    const size_t WT_BYTES = (size_t)512 * 512 * 2; // 512 KB
    unsigned short* Wt = (unsigned short*)ws;
    void* xw = (void*)(ws + WT_BYTES);
    const size_t XW_F32_BYTES = (size_t)M_ROWS * 512 * 4; // 256 MB
    const bool f32path = (ws_size >= WT_BYTES + XW_F32_BYTES);

    k_wt<<<dim3(1024), dim3(256), 0, stream>>>(W, Wt);

    dim3 ggrid(4, 1024); // N-tiles x M-tiles
    if (f32path) {
        k_gemm<true><<<ggrid, dim3(256), 0, stream>>>(x, Wt, xw);
        k_scan<true><<<dim3(128), dim3(512), 0, stream>>>(xw, U, b, out);
    } else {
        k_gemm<false><<<ggrid, dim3(256), 0, stream>>>(x, Wt, xw);
        k_scan<false><<<dim3(128), dim3(512), 0, stream>>>(xw, U, b, out);
    }
}